// Round 1
// baseline (180.655 us; speedup 1.0000x reference)
//
#include <hip/hip_runtime.h>
#include <hip/hip_bf16.h>

#define N_NODES 4096
#define LOG2E 1.44269504088896340736f

typedef __attribute__((ext_vector_type(8))) short bf16x8;
typedef __attribute__((ext_vector_type(4))) float f32x4;

static __device__ __forceinline__ ushort f2bf(float x) {
    union { float f; unsigned u; } v; v.f = x;
    unsigned u = v.u;
    return (ushort)((u + 0x7FFFu + ((u >> 16) & 1u)) >> 16);   // RNE
}
static __device__ __forceinline__ float bf2f(ushort h) {
    union { unsigned u; float f; } v; v.u = ((unsigned)h) << 16; return v.f;
}

// ---------------- mask pack: adj [4096][4096] f32 -> bits [4096][128] u32 ----
__global__ __launch_bounds__(256) void k_pack_mask(const float* __restrict__ adj,
                                                   unsigned* __restrict__ maskw) {
    int idx = blockIdx.x * 256 + threadIdx.x;          // 4096*128 words
    int row = idx >> 7, w = idx & 127;
    const float4* ap = (const float4*)(adj + (size_t)row * N_NODES + w * 32);
    unsigned bits = 0;
#pragma unroll
    for (int q = 0; q < 8; ++q) {
        float4 v = ap[q];
        bits |= (v.x > 0.f ? 1u : 0u) << (q * 4 + 0);
        bits |= (v.y > 0.f ? 1u : 0u) << (q * 4 + 1);
        bits |= (v.z > 0.f ? 1u : 0u) << (q * 4 + 2);
        bits |= (v.w > 0.f ? 1u : 0u) << (q * 4 + 3);
    }
    maskw[idx] = bits;
}

// ---------------- W [h][K][64] f32 -> Wt hi/lo bf16 [h][64][K] (K-major) -----
__global__ void k_prep_w(const float* __restrict__ W, ushort* __restrict__ Wh,
                         ushort* __restrict__ Wl, int kshift, int total) {
    int idx = blockIdx.x * 256 + threadIdx.x;
    if (idx >= total) return;
    int K = 1 << kshift;
    int n = idx & 63;
    int k = (idx >> 6) & (K - 1);
    int h = idx >> (6 + kshift);
    float v = W[idx];
    ushort hi = f2bf(v);
    ushort lo = f2bf(v - bf2f(hi));
    size_t dst = ((size_t)h * 64 + n) * K + k;
    Wh[dst] = hi; Wl[dst] = lo;
}

// ---------------- H = X @ W  (3-term split bf16 MFMA), Hb bf16 [h][4096][64] -
__global__ __launch_bounds__(256) void k_gemm_h(const float* __restrict__ X,
        const ushort* __restrict__ Wh, const ushort* __restrict__ Wl,
        ushort* __restrict__ Hb, int K) {
    int head = blockIdx.y;
    int t = threadIdx.x, wave = t >> 6, lane = t & 63;
    int c = lane & 15, g = lane >> 4;
    int i0 = blockIdx.x * 64 + wave * 16;
    const float* xrow = X + (size_t)(i0 + c) * K;
    f32x4 acc[4] = {};
    for (int k0 = 0; k0 < K; k0 += 32) {
        const float4* xp = (const float4*)(xrow + k0 + g * 8);
        float4 xa = xp[0], xb = xp[1];
        float xs[8] = {xa.x, xa.y, xa.z, xa.w, xb.x, xb.y, xb.z, xb.w};
        union { ushort s[8]; bf16x8 v; } ah, al;
#pragma unroll
        for (int e = 0; e < 8; ++e) {
            ushort hb = f2bf(xs[e]);
            ah.s[e] = hb;
            al.s[e] = f2bf(xs[e] - bf2f(hb));
        }
#pragma unroll
        for (int nt = 0; nt < 4; ++nt) {
            size_t boff = ((size_t)head * 64 + nt * 16 + c) * K + k0 + g * 8;
            bf16x8 bh = *(const bf16x8*)(Wh + boff);
            bf16x8 bl = *(const bf16x8*)(Wl + boff);
            acc[nt] = __builtin_amdgcn_mfma_f32_16x16x32_bf16(ah.v, bh, acc[nt], 0, 0, 0);
            acc[nt] = __builtin_amdgcn_mfma_f32_16x16x32_bf16(al.v, bh, acc[nt], 0, 0, 0);
            acc[nt] = __builtin_amdgcn_mfma_f32_16x16x32_bf16(ah.v, bl, acc[nt], 0, 0, 0);
        }
    }
    ushort* out = Hb + ((size_t)head * N_NODES + i0) * 64;
#pragma unroll
    for (int nt = 0; nt < 4; ++nt)
#pragma unroll
        for (int r = 0; r < 4; ++r)
            out[(g * 4 + r) * 64 + nt * 16 + c] = f2bf(acc[nt][r]);
}

// ---------------- f1/f2 = H . a  (pre-scaled by log2 e) ----------------------
__global__ __launch_bounds__(256) void k_f1f2(const ushort* __restrict__ Hb,
        const float* __restrict__ a, float* __restrict__ f1c, float* __restrict__ f2c) {
    int head = blockIdx.y;
    int t = threadIdx.x, wave = t >> 6, lane = t & 63;
    int i = blockIdx.x * 4 + wave;
    float h = bf2f(Hb[((size_t)head * N_NODES + i) * 64 + lane]);
    float f1 = h * a[head * 128 + lane];
    float f2 = h * a[head * 128 + 64 + lane];
#pragma unroll
    for (int o = 32; o; o >>= 1) { f1 += __shfl_xor(f1, o); f2 += __shfl_xor(f2, o); }
    if (lane == 0) {
        f1c[head * N_NODES + i] = f1 * LOG2E;
        f2c[head * N_NODES + i] = f2 * LOG2E;
    }
}

// ---------------- masked flash attention (fixed shift M=16, no online max) ---
// block = 4 waves; wave w owns rows i0..i0+15; block stages H tile [32j][64n]
// into XOR-swizzled n-major LDS; P built in-register in MFMA A-layout.
__global__ __launch_bounds__(256) void k_attn(const ushort* __restrict__ Hb,
        const float* __restrict__ f1c, const float* __restrict__ f2c,
        const unsigned* __restrict__ maskw,
        float* __restrict__ accP, float* __restrict__ Zp, int JS) {
    int rb = blockIdx.x, js = blockIdx.y, head = blockIdx.z;
    int t = threadIdx.x, wave = t >> 6, lane = t & 63;
    int c = lane & 15, g = lane >> 4;
    int i0 = rb * 64 + wave * 16;
    int irow = i0 + c;
    int jcount = N_NODES / JS;
    int j0 = js * jcount;
    const ushort* H = Hb + (size_t)head * N_NODES * 64;
    float F1 = f1c[head * N_NODES + irow];
    const float* F2 = f2c + (size_t)head * N_NODES;
    const unsigned* mrow = maskw + (size_t)irow * 128;
    const float MC = 16.0f * LOG2E;
    f32x4 acc[4] = {};
    float z = 0.f;
    __shared__ ushort Ht[64 * 40 + 8];

    int sj = t >> 3, sq = t & 7;                 // staging: row j=sj, 8 cols from sq*8
    for (int jt = j0; jt < j0 + jcount; jt += 32) {
        __syncthreads();
        {
            union { int4 v; ushort s[8]; } u;
            u.v = *(const int4*)(H + (size_t)(jt + sj) * 64 + sq * 8);
            int grp = (sj >> 3) ^ (sq & 3);
#pragma unroll
            for (int e = 0; e < 8; ++e) {
                int n = sq * 8 + e;
                Ht[n * 40 + (grp << 3) + (sj & 7)] = u.s[e];
            }
        }
        __syncthreads();

        unsigned w = mrow[jt >> 5];
        unsigned bits = (w >> (g * 8)) & 0xFFu;
        const float4* fp = (const float4*)(F2 + jt + g * 8);
        float4 fa = fp[0], fb = fp[1];
        float f2v[8] = {fa.x, fa.y, fa.z, fa.w, fb.x, fb.y, fb.z, fb.w};
        union { ushort s[8]; bf16x8 v; } pa;
#pragma unroll
        for (int e = 0; e < 8; ++e) {
            float s = F1 + f2v[e];
            float lr = fmaxf(s, 0.2f * s);       // leakyrelu in log2-scaled domain
            float p = __builtin_amdgcn_exp2f(lr - MC);
            p = ((bits >> e) & 1u) ? p : 0.f;
            z += p;
            pa.s[e] = f2bf(p);
        }
#pragma unroll
        for (int nt = 0; nt < 4; ++nt) {
            int n = nt * 16 + c;
            int grp = g ^ ((n >> 3) & 3);
            bf16x8 b = *(const bf16x8*)(&Ht[n * 40 + (grp << 3)]);
            acc[nt] = __builtin_amdgcn_mfma_f32_16x16x32_bf16(pa.v, b, acc[nt], 0, 0, 0);
        }
    }
    z += __shfl_xor(z, 16);
    z += __shfl_xor(z, 32);
    int slice = head * JS + js;
    if (g == 0) Zp[(size_t)slice * N_NODES + irow] = z;
    float* ap = accP + ((size_t)slice * N_NODES + i0) * 64;
#pragma unroll
    for (int nt = 0; nt < 4; ++nt)
#pragma unroll
        for (int r = 0; r < 4; ++r)
            ap[(g * 4 + r) * 64 + nt * 16 + c] = acc[nt][r];
}

// ---------------- combine partials -------------------------------------------
__global__ __launch_bounds__(256) void k_combine1(const float* __restrict__ accP,
        const float* __restrict__ Zp, float* __restrict__ x2, int JS) {
    int idx = blockIdx.x * 256 + threadIdx.x;    // 8*4096*64
    int n = idx & 63, i = (idx >> 6) & 4095, h = idx >> 18;
    float s = 0.f, z = 0.f;
    for (int j = 0; j < JS; ++j) {
        int sl = h * JS + j;
        s += accP[((size_t)sl * N_NODES + i) * 64 + n];
        z += Zp[(size_t)sl * N_NODES + i];
    }
    float v = s / z;
    v = v > 0.f ? v : (__builtin_amdgcn_exp2f(v * LOG2E) - 1.f);   // elu
    x2[(size_t)i * 512 + h * 64 + n] = v;
}

__global__ __launch_bounds__(256) void k_combine2(const float* __restrict__ accP,
        const float* __restrict__ Zp, float* __restrict__ out, int JS) {
    int idx = blockIdx.x * 256 + threadIdx.x;    // 4096*64
    int n = idx & 63, i = idx >> 6;
    float s = 0.f, z = 0.f;
    for (int j = 0; j < JS; ++j) {
        s += accP[((size_t)j * N_NODES + i) * 64 + n];
        z += Zp[(size_t)j * N_NODES + i];
    }
    out[idx] = s / z;
}

extern "C" void kernel_launch(void* const* d_in, const int* in_sizes, int n_in,
                              void* d_out, int out_size, void* d_ws, size_t ws_size,
                              hipStream_t stream) {
    const float* features = (const float*)d_in[0];
    const float* adj      = (const float*)d_in[1];
    const float* W_heads  = (const float*)d_in[2];
    const float* a_heads  = (const float*)d_in[3];
    const float* W_out    = (const float*)d_in[4];
    const float* a_out    = (const float*)d_in[5];
    float* out = (float*)d_out;

    // pick j-split by workspace budget (deterministic: ws_size fixed)
    int JS1 = 2, JS2 = 8;
    {
        size_t need = (size_t)2*1024*1024 + 4*1024*1024 + 512*1024 + 300*1024
                    + 700*1024 + 8*1024*1024
                    + (size_t)16 * N_NODES * 64 * 4 + 16 * N_NODES * 4 + 4096;
        if (ws_size < need) { JS1 = 1; JS2 = 8; }
    }
    int slices = (8 * JS1 > JS2) ? 8 * JS1 : JS2;

    char* ws = (char*)d_ws;
    size_t off = 0;
    auto alloc = [&](size_t bytes) -> void* {
        void* p = ws + off; off = (off + bytes + 255) & ~(size_t)255; return p;
    };
    unsigned* maskw = (unsigned*)alloc((size_t)N_NODES * 128 * 4);
    ushort* Hb1 = (ushort*)alloc((size_t)8 * N_NODES * 64 * 2);
    ushort* Hb2 = (ushort*)alloc((size_t)N_NODES * 64 * 2);
    float* f1c1 = (float*)alloc((size_t)8 * N_NODES * 4);
    float* f2c1 = (float*)alloc((size_t)8 * N_NODES * 4);
    float* f1c2 = (float*)alloc((size_t)N_NODES * 4);
    float* f2c2 = (float*)alloc((size_t)N_NODES * 4);
    ushort* Wh1 = (ushort*)alloc((size_t)8 * 64 * 256 * 2);
    ushort* Wl1 = (ushort*)alloc((size_t)8 * 64 * 256 * 2);
    ushort* Wh2 = (ushort*)alloc((size_t)64 * 512 * 2);
    ushort* Wl2 = (ushort*)alloc((size_t)64 * 512 * 2);
    float* x2   = (float*)alloc((size_t)N_NODES * 512 * 4);
    float* accP = (float*)alloc((size_t)slices * N_NODES * 64 * 4);
    float* Zp   = (float*)alloc((size_t)slices * N_NODES * 4);

    hipLaunchKernelGGL(k_pack_mask, dim3(N_NODES * 128 / 256), dim3(256), 0, stream, adj, maskw);
    hipLaunchKernelGGL(k_prep_w, dim3((8 * 256 * 64 + 255) / 256), dim3(256), 0, stream,
                       W_heads, Wh1, Wl1, 8, 8 * 256 * 64);
    hipLaunchKernelGGL(k_prep_w, dim3((512 * 64 + 255) / 256), dim3(256), 0, stream,
                       W_out, Wh2, Wl2, 9, 512 * 64);
    // layer 1
    hipLaunchKernelGGL(k_gemm_h, dim3(64, 8), dim3(256), 0, stream, features, Wh1, Wl1, Hb1, 256);
    hipLaunchKernelGGL(k_f1f2, dim3(1024, 8), dim3(256), 0, stream, Hb1, a_heads, f1c1, f2c1);
    hipLaunchKernelGGL(k_attn, dim3(64, JS1, 8), dim3(256), 0, stream,
                       Hb1, f1c1, f2c1, maskw, accP, Zp, JS1);
    hipLaunchKernelGGL(k_combine1, dim3(8 * N_NODES * 64 / 256), dim3(256), 0, stream,
                       accP, Zp, x2, JS1);
    // layer 2
    hipLaunchKernelGGL(k_gemm_h, dim3(64, 1), dim3(256), 0, stream, x2, Wh2, Wl2, Hb2, 512);
    hipLaunchKernelGGL(k_f1f2, dim3(1024, 1), dim3(256), 0, stream, Hb2, a_out, f1c2, f2c2);
    hipLaunchKernelGGL(k_attn, dim3(64, JS2, 1), dim3(256), 0, stream,
                       Hb2, f1c2, f2c2, maskw, accP, Zp, JS2);
    hipLaunchKernelGGL(k_combine2, dim3(N_NODES * 64 / 256), dim3(256), 0, stream,
                       accP, Zp, out, JS2);
}